// Round 2
// baseline (205.495 us; speedup 1.0000x reference)
//
#include <hip/hip_runtime.h>
#include <hip/hip_bf16.h>

#define N 8192
#define D 512
#define K_TOP 12
#define THETA 10.0f
#define EPS 1e-8f
#define TAU 0.10f      // candidate threshold; spill+fallback guarantee the guard
#define CAPG 192       // per-row global candidate cap
#define NPAIR 2080     // 64*65/2 upper-triangular 128x128 tile pairs

typedef float f32x16 __attribute__((ext_vector_type(16)));

__device__ __forceinline__ unsigned int bf16_bits_rne(float v) {
    unsigned int u = __float_as_uint(v);
    u += 0x7FFFu + ((u >> 16) & 1u);
    return u >> 16;
}

// async global->LDS DMA, 16B per lane; LDS dest is wave-uniform base + lane*16
__device__ __forceinline__ void load16(const unsigned char* g, unsigned char* l) {
    __builtin_amdgcn_global_load_lds(
        (const __attribute__((address_space(1))) unsigned int*)g,
        (__attribute__((address_space(3))) unsigned int*)l, 16, 0, 0);
}

// -- Kernel 0: row norms -> fp8 e4m3 normalized copy + norms + zero counters --
__global__ __launch_bounds__(256) void norm_kernel(const float* __restrict__ h,
                                                   unsigned char* __restrict__ hq,
                                                   float* __restrict__ norms,
                                                   int* __restrict__ gcnt,
                                                   int* __restrict__ gflag) {
    int row = blockIdx.x * 4 + (threadIdx.x >> 6);
    int lane = threadIdx.x & 63;
    const float4* hr = (const float4*)(h + (size_t)row * D);
    float4 p0 = hr[lane * 2], p1 = hr[lane * 2 + 1];
    float ss = p0.x * p0.x + p0.y * p0.y + p0.z * p0.z + p0.w * p0.w +
               p1.x * p1.x + p1.y * p1.y + p1.z * p1.z + p1.w * p1.w;
#pragma unroll
    for (int off = 32; off > 0; off >>= 1) ss += __shfl_xor(ss, off, 64);
    float nrm = fmaxf(sqrtf(ss), EPS);
    float inv = 1.0f / nrm;
    if (lane == 0) { gcnt[row] = 0; gflag[row] = 0; norms[row] = nrm; }
    unsigned int w0 = __builtin_amdgcn_cvt_pk_fp8_f32(p0.x * inv, p0.y * inv, 0, false);
    w0 = __builtin_amdgcn_cvt_pk_fp8_f32(p0.z * inv, p0.w * inv, w0, true);
    unsigned int w1 = __builtin_amdgcn_cvt_pk_fp8_f32(p1.x * inv, p1.y * inv, 0, false);
    w1 = __builtin_amdgcn_cvt_pk_fp8_f32(p1.z * inv, p1.w * inv, w1, true);
    ((uint2*)(hq + (size_t)row * D))[lane] = make_uint2(w0, w1);
}

// -- Kernel 1: SYMMETRIC fp8 MFMA sim: one 128x128 upper-tri tile-pair/block --
// 2080 blocks, 8 rounds (K=64/round), double-buffered 32 KB LDS, 4 blocks/CU.
// Off-diagonal pairs emit candidates to BOTH row sides (v symmetric);
// diagonal pairs compute the full 128x128 so they emit one-sided.
// Swizzle: 16B chunk kk of row r at slot kk ^ ((r>>2)&3) -> b64 reads at the
// structural 4-cycle floor.
__global__ __launch_bounds__(256, 4) void simfp8_kernel(
        const unsigned char* __restrict__ hq,
        unsigned int* __restrict__ gcand,
        int* __restrict__ gcnt,
        int* __restrict__ gflag) {
    __shared__ unsigned char tiles[2][2][128 * 64];  // [sel][A/B] 32 KB

    // decode pair index -> (it, jt), jt >= it, row-major over the triangle
    const int p = blockIdx.x;
#define CUM(t) (64 * (t) - ((t) * ((t)-1)) / 2)
    int it = (int)((129.0f - sqrtf(16641.0f - 8.0f * (float)p)) * 0.5f);
    while (it > 0 && CUM(it) > p) --it;
    while (CUM(it + 1) <= p) ++it;
    const int jt = it + (p - CUM(it));
#undef CUM
    const int i0 = it * 128, j0 = jt * 128;

    const int t = threadIdx.x;
    const int wave = t >> 6, lane = t & 63;
    const int wr = (wave >> 1) * 64, wc = (wave & 1) * 64;
    const int lm32 = lane & 31, lg2 = lane >> 5;
    const int rk = (lm32 >> 2) & 3;  // read-side swizzle key ((row>>2)&3)

    // staging: chunk c = e*256 + t (e=0,1); row = e*64 + (t>>2), slot = t&3,
    // source chunk q = slot ^ ((row>>2)&3) = (t&3) ^ ((t>>4)&3)
    const int srow = t >> 2;
    const int sq = (t & 3) ^ ((t >> 4) & 3);

    auto issue = [&](int r) {
        int sel = r & 1;
        const unsigned char* gA = hq + (size_t)(i0 + srow) * D + r * 64 + sq * 16;
        const unsigned char* gB = hq + (size_t)(j0 + srow) * D + r * 64 + sq * 16;
        unsigned char* lA = &tiles[sel][0][t * 16];
        unsigned char* lB = &tiles[sel][1][t * 16];
#pragma unroll
        for (int e = 0; e < 2; e++) {
            load16(gA + (size_t)(e * 64) * D, lA + e * 4096);
            load16(gB + (size_t)(e * 64) * D, lB + e * 4096);
        }
    };

    issue(0);

    f32x16 acc[2][2];
#pragma unroll
    for (int x = 0; x < 2; x++)
#pragma unroll
        for (int y = 0; y < 2; y++)
#pragma unroll
            for (int q = 0; q < 16; q++) acc[x][y][q] = 0.f;

    for (int r = 0; r < 8; r++) {
        const int sel = r & 1;

        __builtin_amdgcn_s_barrier();   // prior reads of buffer sel done
        if (r < 7) {
            issue(r + 1);
            asm volatile("s_waitcnt vmcnt(4)" ::: "memory");  // drain round r only
        } else {
            asm volatile("s_waitcnt vmcnt(0)" ::: "memory");
        }
        __builtin_amdgcn_s_barrier();   // round r fully in LDS

#pragma unroll
        for (int kk = 0; kk < 4; kk++) {   // 4 x K16 fp8 MFMA steps = K64
            const int kb = ((kk ^ rk) << 4) + lg2 * 8;  // swizzled byte offset
            long long af[2], bfr[2];
#pragma unroll
            for (int x = 0; x < 2; x++)
                af[x] = *(const long long*)&tiles[sel][0][(wr + x * 32 + lm32) * 64 + kb];
#pragma unroll
            for (int y = 0; y < 2; y++)
                bfr[y] = *(const long long*)&tiles[sel][1][(wc + y * 32 + lm32) * 64 + kb];
#pragma unroll
            for (int x = 0; x < 2; x++)
#pragma unroll
                for (int y = 0; y < 2; y++)
                    acc[x][y] = __builtin_amdgcn_mfma_f32_32x32x16_fp8_fp8(
                        af[x], bfr[y], acc[x][y], 0, 0, 0);
        }
    }

    // epilogue: emit candidates; off-diagonal pairs emit both sides.
    // 32x32 C/D: col = lane&31, row = (reg&3) + 8*(reg>>2) + 4*(lane>>5)
#pragma unroll
    for (int x = 0; x < 2; x++)
#pragma unroll
        for (int y = 0; y < 2; y++) {
            int gcol = j0 + wc + y * 32 + lm32;
#pragma unroll
            for (int q = 0; q < 16; q++) {
                int rr = wr + x * 32 + (q & 3) + 8 * (q >> 2) + 4 * lg2;
                int gi = i0 + rr;
                float v = acc[x][y][q];
                if (gi == gcol) v = 1.0f;   // exact self-similarity (diag tiles)
                if (v > TAU) {
                    unsigned int vb = bf16_bits_rne(v) << 16;
                    int p1 = atomicAdd(&gcnt[gi], 1);
                    if (p1 < CAPG) gcand[(size_t)gi * CAPG + p1] = vb | (unsigned int)gcol;
                    else gflag[gi] = 1;
                    if (it != jt) {   // mirrored entry for the j-side row
                        int p2 = atomicAdd(&gcnt[gcol], 1);
                        if (p2 < CAPG) gcand[(size_t)gcol * CAPG + p2] = vb | (unsigned int)gi;
                        else gflag[gcol] = 1;
                    }
                }
            }
        }
}

// -- Kernel 2: exact top-12 + softmax + gather (fp8 neighbors, fp32 self) --
__global__ __launch_bounds__(256) void gather_kernel(const float* __restrict__ h,
                                                     const unsigned char* __restrict__ hq,
                                                     const float* __restrict__ norms,
                                                     const unsigned int* __restrict__ gcand,
                                                     const int* __restrict__ gcnt,
                                                     const int* __restrict__ gflag,
                                                     float* __restrict__ out) {
    int row = blockIdx.x * 4 + (threadIdx.x >> 6);
    int lane = threadIdx.x & 63;
    int c = gcnt[row];

    float selv[K_TOP];
    int selj[K_TOP];

    if (c >= K_TOP && c <= CAPG && gflag[row] == 0) {
        const unsigned int* cr = gcand + (size_t)row * CAPG;
        unsigned int e[3];
#pragma unroll
        for (int q = 0; q < 3; q++) {
            int idx = lane + 64 * q;
            e[q] = (idx < c) ? cr[idx] : 0u;
        }
#pragma unroll
        for (int k = 0; k < K_TOP; k++) {
            unsigned int m = e[0];
            if (e[1] > m) m = e[1];
            if (e[2] > m) m = e[2];
#pragma unroll
            for (int off = 32; off > 0; off >>= 1) {
                unsigned int om = __shfl_xor(m, off, 64);
                if (om > m) m = om;
            }
            selv[k] = __uint_as_float(m & 0xFFFF0000u);
            selj[k] = (int)(m & 0x1FFFu);
#pragma unroll
            for (int q = 0; q < 3; q++)
                if (e[q] == m) e[q] = 0u;   // entries unique (distinct cols)
        }
    } else {
        // exact brute-force fallback over fp8 rows (rare; cheap insurance)
        float vals[K_TOP];
        int idxs[K_TOP];
#pragma unroll
        for (int q = 0; q < K_TOP; q++) { vals[q] = -3e38f; idxs[q] = 0; }
        float minv = -3e38f;
        int minp = 0;
        const unsigned int* rp = (const unsigned int*)(hq + (size_t)row * D);
        for (int col = lane; col < N; col += 64) {
            const unsigned int* cp = (const unsigned int*)(hq + (size_t)col * D);
            float s = 0.f;
            for (int k4 = 0; k4 < D / 4; k4++) {
                unsigned int ra = rp[k4], ca = cp[k4];
                s += __builtin_amdgcn_cvt_f32_fp8(ra, 0) * __builtin_amdgcn_cvt_f32_fp8(ca, 0);
                s += __builtin_amdgcn_cvt_f32_fp8(ra, 1) * __builtin_amdgcn_cvt_f32_fp8(ca, 1);
                s += __builtin_amdgcn_cvt_f32_fp8(ra, 2) * __builtin_amdgcn_cvt_f32_fp8(ca, 2);
                s += __builtin_amdgcn_cvt_f32_fp8(ra, 3) * __builtin_amdgcn_cvt_f32_fp8(ca, 3);
            }
            if (col == row) s = 1.0f;
            if (s > minv) {
                vals[minp] = s; idxs[minp] = col;
                minv = vals[0]; minp = 0;
#pragma unroll
                for (int q = 1; q < K_TOP; q++)
                    if (vals[q] < minv) { minv = vals[q]; minp = q; }
            }
        }
        for (int k = 0; k < K_TOP; k++) {
            float bv = vals[0]; int bp = 0;
#pragma unroll
            for (int q = 1; q < K_TOP; q++)
                if (vals[q] > bv) { bv = vals[q]; bp = q; }
            float v = bv; int j = idxs[bp]; int src = lane;
#pragma unroll
            for (int off = 32; off > 0; off >>= 1) {
                float ov = __shfl_xor(v, off, 64);
                int oj = __shfl_xor(j, off, 64);
                int os = __shfl_xor(src, off, 64);
                if (ov > v || (ov == v && os < src)) { v = ov; j = oj; src = os; }
            }
            selv[k] = __uint_as_float((unsigned int)(bf16_bits_rne(v) << 16));
            selj[k] = j;
            if (lane == src) vals[bp] = -3e38f;
        }
    }

    float mx = selv[0];
    float beta[K_TOP];
    float sum = 0.f;
#pragma unroll
    for (int q = 0; q < K_TOP; q++) { beta[q] = __expf(THETA * (selv[q] - mx)); sum += beta[q]; }
    float rs = 1.0f / sum;

    // lane owns output elements [lane*8, lane*8+8)
    float acc[8];
#pragma unroll
    for (int ee = 0; ee < 8; ee++) acc[ee] = 0.f;
#pragma unroll
    for (int q = 0; q < K_TOP; q++) {
        int j = selj[q];
        float w = beta[q] * rs;
        if (j == row) {   // wave-uniform; dominant term stays fp32-exact
            const float4* hr = (const float4*)(h + (size_t)row * D);
            float4 p0 = hr[lane * 2], p1 = hr[lane * 2 + 1];
            acc[0] += w * p0.x; acc[1] += w * p0.y; acc[2] += w * p0.z; acc[3] += w * p0.w;
            acc[4] += w * p1.x; acc[5] += w * p1.y; acc[6] += w * p1.z; acc[7] += w * p1.w;
        } else {          // neighbors (weight ~2e-4): fp8 row x norm
            float wj = w * norms[j];
            uint2 hv = ((const uint2*)(hq + (size_t)j * D))[lane];
            acc[0] += wj * __builtin_amdgcn_cvt_f32_fp8(hv.x, 0);
            acc[1] += wj * __builtin_amdgcn_cvt_f32_fp8(hv.x, 1);
            acc[2] += wj * __builtin_amdgcn_cvt_f32_fp8(hv.x, 2);
            acc[3] += wj * __builtin_amdgcn_cvt_f32_fp8(hv.x, 3);
            acc[4] += wj * __builtin_amdgcn_cvt_f32_fp8(hv.y, 0);
            acc[5] += wj * __builtin_amdgcn_cvt_f32_fp8(hv.y, 1);
            acc[6] += wj * __builtin_amdgcn_cvt_f32_fp8(hv.y, 2);
            acc[7] += wj * __builtin_amdgcn_cvt_f32_fp8(hv.y, 3);
        }
    }
    float4* orow = (float4*)(out + (size_t)row * D);
    orow[lane * 2] = make_float4(acc[0], acc[1], acc[2], acc[3]);
    orow[lane * 2 + 1] = make_float4(acc[4], acc[5], acc[6], acc[7]);
}

extern "C" void kernel_launch(void* const* d_in, const int* in_sizes, int n_in,
                              void* d_out, int out_size, void* d_ws, size_t ws_size,
                              hipStream_t stream) {
    const float* h = (const float*)d_in[0];
    float* out = (float*)d_out;

    char* ws = (char*)d_ws;
    unsigned char* hq = (unsigned char*)ws;                      // 4 MB fp8
    size_t off = (size_t)N * D;
    float* norms = (float*)(ws + off);                           // 32 KB
    int* gcnt = (int*)(ws + off + (size_t)N * 4);                // 32 KB
    int* gflag = (int*)(ws + off + (size_t)N * 8);               // 32 KB
    unsigned int* gcand = (unsigned int*)(ws + off + (size_t)N * 12);  // 6 MB

    norm_kernel<<<N / 4, 256, 0, stream>>>(h, hq, norms, gcnt, gflag);
    simfp8_kernel<<<NPAIR, 256, 0, stream>>>(hq, gcand, gcnt, gflag);
    gather_kernel<<<N / 4, 256, 0, stream>>>(h, hq, norms, gcand, gcnt, gflag, out);
}

// Round 3
// 137.054 us; speedup vs baseline: 1.4994x; 1.4994x over previous
//
#include <hip/hip_runtime.h>
#include <hip/hip_bf16.h>

#define N 8192
#define D 512
#define K_TOP 12
#define THETA 10.0f
#define EPS 1e-8f
#define TAU 0.10f      // candidate threshold; spill+fallback guarantee the guard
#define CAPL 6         // per-row per-pair LDS cap (overflow -> exact global spill)
#define CAPG 192       // per-row global candidate cap
#define NPAIR 2080     // 64*65/2 upper-triangular 128x128 tile pairs
#define NBLK 1024      // persistent blocks: exactly 4/CU, one generation

typedef float f32x16 __attribute__((ext_vector_type(16)));

__device__ __forceinline__ unsigned int bf16_bits_rne(float v) {
    unsigned int u = __float_as_uint(v);
    u += 0x7FFFu + ((u >> 16) & 1u);
    return u >> 16;
}

// async global->LDS DMA, 16B per lane; LDS dest is wave-uniform base + lane*16
__device__ __forceinline__ void load16(const unsigned char* g, unsigned char* l) {
    __builtin_amdgcn_global_load_lds(
        (const __attribute__((address_space(1))) unsigned int*)g,
        (__attribute__((address_space(3))) unsigned int*)l, 16, 0, 0);
}

// column-major (jt-major) triangle decode: p = jt*(jt+1)/2 + it, it in [0,jt]
__device__ __forceinline__ void decode_pair(int p, int& it, int& jt) {
    int j = (int)((sqrtf(8.0f * (float)p + 1.0f) - 1.0f) * 0.5f);
    while ((j + 1) * (j + 2) / 2 <= p) ++j;
    while (j * (j + 1) / 2 > p) --j;
    jt = j;
    it = p - j * (j + 1) / 2;
}

// -- Kernel 0: row norms -> fp8 e4m3 normalized copy + norms + zero counters --
__global__ __launch_bounds__(256) void norm_kernel(const float* __restrict__ h,
                                                   unsigned char* __restrict__ hq,
                                                   float* __restrict__ norms,
                                                   int* __restrict__ gcnt,
                                                   int* __restrict__ gflag) {
    int row = blockIdx.x * 4 + (threadIdx.x >> 6);
    int lane = threadIdx.x & 63;
    const float4* hr = (const float4*)(h + (size_t)row * D);
    float4 p0 = hr[lane * 2], p1 = hr[lane * 2 + 1];
    float ss = p0.x * p0.x + p0.y * p0.y + p0.z * p0.z + p0.w * p0.w +
               p1.x * p1.x + p1.y * p1.y + p1.z * p1.z + p1.w * p1.w;
#pragma unroll
    for (int off = 32; off > 0; off >>= 1) ss += __shfl_xor(ss, off, 64);
    float nrm = fmaxf(sqrtf(ss), EPS);
    float inv = 1.0f / nrm;
    if (lane == 0) { gcnt[row] = 0; gflag[row] = 0; norms[row] = nrm; }
    unsigned int w0 = __builtin_amdgcn_cvt_pk_fp8_f32(p0.x * inv, p0.y * inv, 0, false);
    w0 = __builtin_amdgcn_cvt_pk_fp8_f32(p0.z * inv, p0.w * inv, w0, true);
    unsigned int w1 = __builtin_amdgcn_cvt_pk_fp8_f32(p1.x * inv, p1.y * inv, 0, false);
    w1 = __builtin_amdgcn_cvt_pk_fp8_f32(p1.z * inv, p1.w * inv, w1, true);
    ((uint2*)(hq + (size_t)row * D))[lane] = make_uint2(w0, w1);
}

// -- Kernel 1: SYMMETRIC fp8 MFMA sim, persistent blocks over tile-pairs --
// 1024 blocks x (2-3 pairs each), 8 rounds/pair (K=64), double-buffered 32 KB
// tiles, pipeline primed across pair boundaries. Candidates buffered two-sided
// in LDS (i-rows + j-rows), flushed once per pair with batched atomics.
// LDS total 39936 B -> 4 blocks/CU.
__global__ __launch_bounds__(256, 4) void simfp8_kernel(
        const unsigned char* __restrict__ hq,
        unsigned int* __restrict__ gcand,
        int* __restrict__ gcnt,
        int* __restrict__ gflag) {
    __shared__ unsigned char tiles[2][2][128 * 64];  // [sel][A/B] 32 KB
    __shared__ int cnt[256];                          // 1 KB
    __shared__ unsigned int lbuf[256][CAPL];          // 6 KB

    const int b = blockIdx.x;
    const int t = threadIdx.x;
    const int wave = t >> 6, lane = t & 63;
    const int wr = (wave >> 1) * 64, wc = (wave & 1) * 64;
    const int lm32 = lane & 31, lg2 = lane >> 5;
    const int rk = (lm32 >> 2) & 3;  // read-side swizzle key ((row>>2)&3)

    // staging: chunk c = e*256 + t (e=0,1); row = e*64 + (t>>2), slot = t&3,
    // source chunk q = slot ^ ((row>>2)&3) = (t&3) ^ ((t>>4)&3)
    const int srow = t >> 2;
    const int sq = (t & 3) ^ ((t >> 4) & 3);

    cnt[t] = 0;   // ordered before first emit by the round barriers

    auto issue = [&](int ii0, int jj0, int r_) {
        int sel = r_ & 1;   // pair length 8 rounds (even) keeps parity global
        const unsigned char* gA = hq + (size_t)(ii0 + srow) * D + r_ * 64 + sq * 16;
        const unsigned char* gB = hq + (size_t)(jj0 + srow) * D + r_ * 64 + sq * 16;
        unsigned char* lA = &tiles[sel][0][t * 16];
        unsigned char* lB = &tiles[sel][1][t * 16];
#pragma unroll
        for (int e = 0; e < 2; e++) {
            load16(gA + (size_t)(e * 64) * D, lA + e * 4096);
            load16(gB + (size_t)(e * 64) * D, lB + e * 4096);
        }
    };

    const int nloc = (b + 2048 < NPAIR) ? 3 : 2;   // blocks 0..31 take a 3rd pair

    int it, jt;
    decode_pair(b, it, jt);
    int ci0 = it * 128, cj0 = jt * 128;
    bool cdiag = (it == jt);
    issue(ci0, cj0, 0);

    f32x16 acc[2][2];
#pragma unroll
    for (int x = 0; x < 2; x++)
#pragma unroll
        for (int y = 0; y < 2; y++)
#pragma unroll
            for (int q = 0; q < 16; q++) acc[x][y][q] = 0.f;

    for (int qp = 0; qp < nloc; qp++) {
        int ni0 = 0, nj0 = 0;
        bool ndiag = false;
        if (qp + 1 < nloc) {
            int i2, j2;
            decode_pair(b + (qp + 1) * NBLK, i2, j2);
            ni0 = i2 * 128; nj0 = j2 * 128; ndiag = (i2 == j2);
        }

        for (int r = 0; r < 8; r++) {
            const int sel = r & 1;

            __builtin_amdgcn_s_barrier();   // prior reads of buffer sel done
            if (r < 7) {
                issue(ci0, cj0, r + 1);
                asm volatile("s_waitcnt vmcnt(4)" ::: "memory");  // drain round r
            } else if (qp + 1 < nloc) {
                issue(ni0, nj0, 0);          // prime next pair's round 0
                asm volatile("s_waitcnt vmcnt(4)" ::: "memory");
            } else {
                asm volatile("s_waitcnt vmcnt(0)" ::: "memory");
            }
            __builtin_amdgcn_s_barrier();   // round r fully in LDS

#pragma unroll
            for (int kk = 0; kk < 4; kk++) {   // 4 x K16 fp8 MFMA steps = K64
                const int kb = ((kk ^ rk) << 4) + lg2 * 8;  // swizzled byte offset
                long long af[2], bfr[2];
#pragma unroll
                for (int x = 0; x < 2; x++)
                    af[x] = *(const long long*)&tiles[sel][0][(wr + x * 32 + lm32) * 64 + kb];
#pragma unroll
                for (int y = 0; y < 2; y++)
                    bfr[y] = *(const long long*)&tiles[sel][1][(wc + y * 32 + lm32) * 64 + kb];
#pragma unroll
                for (int x = 0; x < 2; x++)
#pragma unroll
                    for (int y = 0; y < 2; y++)
                        acc[x][y] = __builtin_amdgcn_mfma_f32_32x32x16_fp8_fp8(
                            af[x], bfr[y], acc[x][y], 0, 0, 0);
            }
        }

        // emit candidates to two-sided LDS buffer; reset acc for next pair.
        // 32x32 C/D: col = lane&31, row = (reg&3) + 8*(reg>>2) + 4*(lane>>5)
#pragma unroll
        for (int x = 0; x < 2; x++)
#pragma unroll
            for (int y = 0; y < 2; y++) {
                int lcol = wc + y * 32 + lm32;
                int gcol = cj0 + lcol;
#pragma unroll
                for (int q = 0; q < 16; q++) {
                    int rr = wr + x * 32 + (q & 3) + 8 * (q >> 2) + 4 * lg2;
                    int gi = ci0 + rr;
                    float v = acc[x][y][q];
                    acc[x][y][q] = 0.f;
                    if (gi == gcol) v = 1.0f;   // exact self-sim (diag pairs only)
                    if (v > TAU) {
                        unsigned int vb = bf16_bits_rne(v) << 16;
                        int idx = atomicAdd(&cnt[rr], 1);
                        if (idx < CAPL) lbuf[rr][idx] = vb | (unsigned int)gcol;
                        else {  // rare exact spill straight to global
                            int pg = atomicAdd(&gcnt[gi], 1);
                            if (pg < CAPG) gcand[(size_t)gi * CAPG + pg] = vb | (unsigned int)gcol;
                            else gflag[gi] = 1;
                        }
                        if (!cdiag) {   // mirrored entry for the j-side row
                            int idx2 = atomicAdd(&cnt[128 + lcol], 1);
                            if (idx2 < CAPL) lbuf[128 + lcol][idx2] = vb | (unsigned int)gi;
                            else {
                                int pg = atomicAdd(&gcnt[gcol], 1);
                                if (pg < CAPG) gcand[(size_t)gcol * CAPG + pg] = vb | (unsigned int)gi;
                                else gflag[gcol] = 1;
                            }
                        }
                    }
                }
            }

        __syncthreads();   // all emissions visible (drains vmcnt too; rare path)
        {
            int grow = (t < 128) ? (ci0 + t) : (cj0 + t - 128);
            int c = cnt[t];
            int s = c < CAPL ? c : CAPL;
            if (s > 0) {   // diag pairs: j-side cnt stays 0, auto-skipped
                int base = atomicAdd(&gcnt[grow], s);
                unsigned int* dst = gcand + (size_t)grow * CAPG;
                for (int k = 0; k < s; k++) {
                    int pp = base + k;
                    if (pp < CAPG) dst[pp] = lbuf[t][k];
                    else gflag[grow] = 1;
                }
            }
            cnt[t] = 0;   // owner-thread reset; next emit is 8 barriers away
        }

        ci0 = ni0; cj0 = nj0; cdiag = ndiag;
    }
}

// -- Kernel 2: exact top-12 + softmax + gather (fp8 neighbors, fp32 self) --
__global__ __launch_bounds__(256) void gather_kernel(const float* __restrict__ h,
                                                     const unsigned char* __restrict__ hq,
                                                     const float* __restrict__ norms,
                                                     const unsigned int* __restrict__ gcand,
                                                     const int* __restrict__ gcnt,
                                                     const int* __restrict__ gflag,
                                                     float* __restrict__ out) {
    int row = blockIdx.x * 4 + (threadIdx.x >> 6);
    int lane = threadIdx.x & 63;
    int c = gcnt[row];

    float selv[K_TOP];
    int selj[K_TOP];

    if (c >= K_TOP && c <= CAPG && gflag[row] == 0) {
        const unsigned int* cr = gcand + (size_t)row * CAPG;
        unsigned int e[3];
#pragma unroll
        for (int q = 0; q < 3; q++) {
            int idx = lane + 64 * q;
            e[q] = (idx < c) ? cr[idx] : 0u;
        }
#pragma unroll
        for (int k = 0; k < K_TOP; k++) {
            unsigned int m = e[0];
            if (e[1] > m) m = e[1];
            if (e[2] > m) m = e[2];
#pragma unroll
            for (int off = 32; off > 0; off >>= 1) {
                unsigned int om = __shfl_xor(m, off, 64);
                if (om > m) m = om;
            }
            selv[k] = __uint_as_float(m & 0xFFFF0000u);
            selj[k] = (int)(m & 0x1FFFu);
#pragma unroll
            for (int q = 0; q < 3; q++)
                if (e[q] == m) e[q] = 0u;   // entries unique (distinct cols)
        }
    } else {
        // exact brute-force fallback over fp8 rows (rare; cheap insurance)
        float vals[K_TOP];
        int idxs[K_TOP];
#pragma unroll
        for (int q = 0; q < K_TOP; q++) { vals[q] = -3e38f; idxs[q] = 0; }
        float minv = -3e38f;
        int minp = 0;
        const unsigned int* rp = (const unsigned int*)(hq + (size_t)row * D);
        for (int col = lane; col < N; col += 64) {
            const unsigned int* cp = (const unsigned int*)(hq + (size_t)col * D);
            float s = 0.f;
            for (int k4 = 0; k4 < D / 4; k4++) {
                unsigned int ra = rp[k4], ca = cp[k4];
                s += __builtin_amdgcn_cvt_f32_fp8(ra, 0) * __builtin_amdgcn_cvt_f32_fp8(ca, 0);
                s += __builtin_amdgcn_cvt_f32_fp8(ra, 1) * __builtin_amdgcn_cvt_f32_fp8(ca, 1);
                s += __builtin_amdgcn_cvt_f32_fp8(ra, 2) * __builtin_amdgcn_cvt_f32_fp8(ca, 2);
                s += __builtin_amdgcn_cvt_f32_fp8(ra, 3) * __builtin_amdgcn_cvt_f32_fp8(ca, 3);
            }
            if (col == row) s = 1.0f;
            if (s > minv) {
                vals[minp] = s; idxs[minp] = col;
                minv = vals[0]; minp = 0;
#pragma unroll
                for (int q = 1; q < K_TOP; q++)
                    if (vals[q] < minv) { minv = vals[q]; minp = q; }
            }
        }
        for (int k = 0; k < K_TOP; k++) {
            float bv = vals[0]; int bp = 0;
#pragma unroll
            for (int q = 1; q < K_TOP; q++)
                if (vals[q] > bv) { bv = vals[q]; bp = q; }
            float v = bv; int j = idxs[bp]; int src = lane;
#pragma unroll
            for (int off = 32; off > 0; off >>= 1) {
                float ov = __shfl_xor(v, off, 64);
                int oj = __shfl_xor(j, off, 64);
                int os = __shfl_xor(src, off, 64);
                if (ov > v || (ov == v && os < src)) { v = ov; j = oj; src = os; }
            }
            selv[k] = __uint_as_float((unsigned int)(bf16_bits_rne(v) << 16));
            selj[k] = j;
            if (lane == src) vals[bp] = -3e38f;
        }
    }

    float mx = selv[0];
    float beta[K_TOP];
    float sum = 0.f;
#pragma unroll
    for (int q = 0; q < K_TOP; q++) { beta[q] = __expf(THETA * (selv[q] - mx)); sum += beta[q]; }
    float rs = 1.0f / sum;

    // lane owns output elements [lane*8, lane*8+8)
    float acc[8];
#pragma unroll
    for (int ee = 0; ee < 8; ee++) acc[ee] = 0.f;
#pragma unroll
    for (int q = 0; q < K_TOP; q++) {
        int j = selj[q];
        float w = beta[q] * rs;
        if (j == row) {   // wave-uniform; dominant term stays fp32-exact
            const float4* hr = (const float4*)(h + (size_t)row * D);
            float4 p0 = hr[lane * 2], p1 = hr[lane * 2 + 1];
            acc[0] += w * p0.x; acc[1] += w * p0.y; acc[2] += w * p0.z; acc[3] += w * p0.w;
            acc[4] += w * p1.x; acc[5] += w * p1.y; acc[6] += w * p1.z; acc[7] += w * p1.w;
        } else {          // neighbors (weight ~2e-4): fp8 row x norm
            float wj = w * norms[j];
            uint2 hv = ((const uint2*)(hq + (size_t)j * D))[lane];
            acc[0] += wj * __builtin_amdgcn_cvt_f32_fp8(hv.x, 0);
            acc[1] += wj * __builtin_amdgcn_cvt_f32_fp8(hv.x, 1);
            acc[2] += wj * __builtin_amdgcn_cvt_f32_fp8(hv.x, 2);
            acc[3] += wj * __builtin_amdgcn_cvt_f32_fp8(hv.x, 3);
            acc[4] += wj * __builtin_amdgcn_cvt_f32_fp8(hv.y, 0);
            acc[5] += wj * __builtin_amdgcn_cvt_f32_fp8(hv.y, 1);
            acc[6] += wj * __builtin_amdgcn_cvt_f32_fp8(hv.y, 2);
            acc[7] += wj * __builtin_amdgcn_cvt_f32_fp8(hv.y, 3);
        }
    }
    float4* orow = (float4*)(out + (size_t)row * D);
    orow[lane * 2] = make_float4(acc[0], acc[1], acc[2], acc[3]);
    orow[lane * 2 + 1] = make_float4(acc[4], acc[5], acc[6], acc[7]);
}

extern "C" void kernel_launch(void* const* d_in, const int* in_sizes, int n_in,
                              void* d_out, int out_size, void* d_ws, size_t ws_size,
                              hipStream_t stream) {
    const float* h = (const float*)d_in[0];
    float* out = (float*)d_out;

    char* ws = (char*)d_ws;
    unsigned char* hq = (unsigned char*)ws;                      // 4 MB fp8
    size_t off = (size_t)N * D;
    float* norms = (float*)(ws + off);                           // 32 KB
    int* gcnt = (int*)(ws + off + (size_t)N * 4);                // 32 KB
    int* gflag = (int*)(ws + off + (size_t)N * 8);               // 32 KB
    unsigned int* gcand = (unsigned int*)(ws + off + (size_t)N * 12);  // 6 MB

    norm_kernel<<<N / 4, 256, 0, stream>>>(h, hq, norms, gcnt, gflag);
    simfp8_kernel<<<NBLK, 256, 0, stream>>>(hq, gcand, gcnt, gflag);
    gather_kernel<<<N / 4, 256, 0, stream>>>(h, hq, norms, gcand, gcnt, gflag, out);
}

// Round 4
// 132.512 us; speedup vs baseline: 1.5508x; 1.0343x over previous
//
#include <hip/hip_runtime.h>
#include <hip/hip_bf16.h>

#define N 8192
#define D 512
#define K_TOP 12
#define THETA 10.0f
#define EPS 1e-8f
#define TAU 0.10f      // candidate threshold; spill+fallback guarantee the guard
#define CAPL 6         // per-row per-pair LDS cap (overflow -> exact global spill)
#define CAPG 192       // per-row global candidate cap
#define NPAIR 2080     // 64*65/2 upper-triangular 128x128 tile pairs
#define NBLK 1024      // persistent blocks: exactly 4/CU, one generation

typedef float f32x16 __attribute__((ext_vector_type(16)));

__device__ __forceinline__ unsigned int bf16_bits_rne(float v) {
    unsigned int u = __float_as_uint(v);
    u += 0x7FFFu + ((u >> 16) & 1u);
    return u >> 16;
}

// async global->LDS DMA, 16B per lane; LDS dest is wave-uniform base + lane*16
__device__ __forceinline__ void load16(const unsigned char* g, unsigned char* l) {
    __builtin_amdgcn_global_load_lds(
        (const __attribute__((address_space(1))) unsigned int*)g,
        (__attribute__((address_space(3))) unsigned int*)l, 16, 0, 0);
}

// column-major (jt-major) triangle decode: p = jt*(jt+1)/2 + it, it in [0,jt]
__device__ __forceinline__ void decode_pair(int p, int& it, int& jt) {
    int j = (int)((sqrtf(8.0f * (float)p + 1.0f) - 1.0f) * 0.5f);
    while ((j + 1) * (j + 2) / 2 <= p) ++j;
    while (j * (j + 1) / 2 > p) --j;
    jt = j;
    it = p - j * (j + 1) / 2;
}

// -- Kernel 0: row norms -> fp8 e4m3 normalized copy + norms + zero counters --
// Dense lane mapping: lane owns elems [lane*4,+4) and [256+lane*4,+4) so every
// wave load is a full 1KB transaction and every store a full 256B transaction.
__global__ __launch_bounds__(256) void norm_kernel(const float* __restrict__ h,
                                                   unsigned char* __restrict__ hq,
                                                   float* __restrict__ norms,
                                                   int* __restrict__ gcnt,
                                                   int* __restrict__ gflag) {
    int row = blockIdx.x * 4 + (threadIdx.x >> 6);
    int lane = threadIdx.x & 63;
    const float4* hr4 = (const float4*)(h + (size_t)row * D);
    float4 p0 = hr4[lane], p1 = hr4[64 + lane];
    float ss = p0.x * p0.x + p0.y * p0.y + p0.z * p0.z + p0.w * p0.w +
               p1.x * p1.x + p1.y * p1.y + p1.z * p1.z + p1.w * p1.w;
#pragma unroll
    for (int off = 32; off > 0; off >>= 1) ss += __shfl_xor(ss, off, 64);
    float nrm = fmaxf(sqrtf(ss), EPS);
    float inv = 1.0f / nrm;
    if (lane == 0) { gcnt[row] = 0; gflag[row] = 0; norms[row] = nrm; }
    unsigned int w0 = __builtin_amdgcn_cvt_pk_fp8_f32(p0.x * inv, p0.y * inv, 0, false);
    w0 = __builtin_amdgcn_cvt_pk_fp8_f32(p0.z * inv, p0.w * inv, w0, true);
    unsigned int w1 = __builtin_amdgcn_cvt_pk_fp8_f32(p1.x * inv, p1.y * inv, 0, false);
    w1 = __builtin_amdgcn_cvt_pk_fp8_f32(p1.z * inv, p1.w * inv, w1, true);
    unsigned int* q32 = (unsigned int*)(hq + (size_t)row * D);
    q32[lane] = w0;
    q32[64 + lane] = w1;
}

// -- Kernel 1: SYMMETRIC fp8 MFMA sim, persistent blocks over tile-pairs --
// (unchanged from R3: 54.5 us, MfmaUtil 23.6%, bank conflicts at the 4-phase
// structural floor for 512B b64 reads)
__global__ __launch_bounds__(256, 4) void simfp8_kernel(
        const unsigned char* __restrict__ hq,
        unsigned int* __restrict__ gcand,
        int* __restrict__ gcnt,
        int* __restrict__ gflag) {
    __shared__ unsigned char tiles[2][2][128 * 64];  // [sel][A/B] 32 KB
    __shared__ int cnt[256];                          // 1 KB
    __shared__ unsigned int lbuf[256][CAPL];          // 6 KB

    const int b = blockIdx.x;
    const int t = threadIdx.x;
    const int wave = t >> 6, lane = t & 63;
    const int wr = (wave >> 1) * 64, wc = (wave & 1) * 64;
    const int lm32 = lane & 31, lg2 = lane >> 5;
    const int rk = (lm32 >> 2) & 3;  // read-side swizzle key ((row>>2)&3)

    const int srow = t >> 2;
    const int sq = (t & 3) ^ ((t >> 4) & 3);

    cnt[t] = 0;   // ordered before first emit by the round barriers

    auto issue = [&](int ii0, int jj0, int r_) {
        int sel = r_ & 1;   // pair length 8 rounds (even) keeps parity global
        const unsigned char* gA = hq + (size_t)(ii0 + srow) * D + r_ * 64 + sq * 16;
        const unsigned char* gB = hq + (size_t)(jj0 + srow) * D + r_ * 64 + sq * 16;
        unsigned char* lA = &tiles[sel][0][t * 16];
        unsigned char* lB = &tiles[sel][1][t * 16];
#pragma unroll
        for (int e = 0; e < 2; e++) {
            load16(gA + (size_t)(e * 64) * D, lA + e * 4096);
            load16(gB + (size_t)(e * 64) * D, lB + e * 4096);
        }
    };

    const int nloc = (b + 2048 < NPAIR) ? 3 : 2;   // blocks 0..31 take a 3rd pair

    int it, jt;
    decode_pair(b, it, jt);
    int ci0 = it * 128, cj0 = jt * 128;
    bool cdiag = (it == jt);
    issue(ci0, cj0, 0);

    f32x16 acc[2][2];
#pragma unroll
    for (int x = 0; x < 2; x++)
#pragma unroll
        for (int y = 0; y < 2; y++)
#pragma unroll
            for (int q = 0; q < 16; q++) acc[x][y][q] = 0.f;

    for (int qp = 0; qp < nloc; qp++) {
        int ni0 = 0, nj0 = 0;
        bool ndiag = false;
        if (qp + 1 < nloc) {
            int i2, j2;
            decode_pair(b + (qp + 1) * NBLK, i2, j2);
            ni0 = i2 * 128; nj0 = j2 * 128; ndiag = (i2 == j2);
        }

        for (int r = 0; r < 8; r++) {
            const int sel = r & 1;

            __builtin_amdgcn_s_barrier();   // prior reads of buffer sel done
            if (r < 7) {
                issue(ci0, cj0, r + 1);
                asm volatile("s_waitcnt vmcnt(4)" ::: "memory");  // drain round r
            } else if (qp + 1 < nloc) {
                issue(ni0, nj0, 0);          // prime next pair's round 0
                asm volatile("s_waitcnt vmcnt(4)" ::: "memory");
            } else {
                asm volatile("s_waitcnt vmcnt(0)" ::: "memory");
            }
            __builtin_amdgcn_s_barrier();   // round r fully in LDS

#pragma unroll
            for (int kk = 0; kk < 4; kk++) {   // 4 x K16 fp8 MFMA steps = K64
                const int kb = ((kk ^ rk) << 4) + lg2 * 8;  // swizzled byte offset
                long long af[2], bfr[2];
#pragma unroll
                for (int x = 0; x < 2; x++)
                    af[x] = *(const long long*)&tiles[sel][0][(wr + x * 32 + lm32) * 64 + kb];
#pragma unroll
                for (int y = 0; y < 2; y++)
                    bfr[y] = *(const long long*)&tiles[sel][1][(wc + y * 32 + lm32) * 64 + kb];
#pragma unroll
                for (int x = 0; x < 2; x++)
#pragma unroll
                    for (int y = 0; y < 2; y++)
                        acc[x][y] = __builtin_amdgcn_mfma_f32_32x32x16_fp8_fp8(
                            af[x], bfr[y], acc[x][y], 0, 0, 0);
            }
        }

        // emit candidates to two-sided LDS buffer; reset acc for next pair.
        // 32x32 C/D: col = lane&31, row = (reg&3) + 8*(reg>>2) + 4*(lane>>5)
#pragma unroll
        for (int x = 0; x < 2; x++)
#pragma unroll
            for (int y = 0; y < 2; y++) {
                int lcol = wc + y * 32 + lm32;
                int gcol = cj0 + lcol;
#pragma unroll
                for (int q = 0; q < 16; q++) {
                    int rr = wr + x * 32 + (q & 3) + 8 * (q >> 2) + 4 * lg2;
                    int gi = ci0 + rr;
                    float v = acc[x][y][q];
                    acc[x][y][q] = 0.f;
                    if (gi == gcol) v = 1.0f;   // exact self-sim (diag pairs only)
                    if (v > TAU) {
                        unsigned int vb = bf16_bits_rne(v) << 16;
                        int idx = atomicAdd(&cnt[rr], 1);
                        if (idx < CAPL) lbuf[rr][idx] = vb | (unsigned int)gcol;
                        else {  // rare exact spill straight to global
                            int pg = atomicAdd(&gcnt[gi], 1);
                            if (pg < CAPG) gcand[(size_t)gi * CAPG + pg] = vb | (unsigned int)gcol;
                            else gflag[gi] = 1;
                        }
                        if (!cdiag) {   // mirrored entry for the j-side row
                            int idx2 = atomicAdd(&cnt[128 + lcol], 1);
                            if (idx2 < CAPL) lbuf[128 + lcol][idx2] = vb | (unsigned int)gi;
                            else {
                                int pg = atomicAdd(&gcnt[gcol], 1);
                                if (pg < CAPG) gcand[(size_t)gcol * CAPG + pg] = vb | (unsigned int)gi;
                                else gflag[gcol] = 1;
                            }
                        }
                    }
                }
            }

        __syncthreads();   // all emissions visible (drains vmcnt too; rare path)
        {
            int grow = (t < 128) ? (ci0 + t) : (cj0 + t - 128);
            int c = cnt[t];
            int s = c < CAPL ? c : CAPL;
            if (s > 0) {   // diag pairs: j-side cnt stays 0, auto-skipped
                int base = atomicAdd(&gcnt[grow], s);
                unsigned int* dst = gcand + (size_t)grow * CAPG;
                for (int k = 0; k < s; k++) {
                    int pp = base + k;
                    if (pp < CAPG) dst[pp] = lbuf[t][k];
                    else gflag[grow] = 1;
                }
            }
            cnt[t] = 0;   // owner-thread reset; next emit is 8 barriers away
        }

        ci0 = ni0; cj0 = nj0; cdiag = ndiag;
    }
}

// -- Kernel 2: exact top-12 + softmax + gather (fp8 neighbors, fp32 self) --
// Dense lane mapping (lane*4 / 256+lane*4) for all row-wide loads/stores;
// self-row prefetched at entry; neighbor rows batch-loaded 12-deep before FMA.
__global__ __launch_bounds__(256) void gather_kernel(const float* __restrict__ h,
                                                     const unsigned char* __restrict__ hq,
                                                     const float* __restrict__ norms,
                                                     const unsigned int* __restrict__ gcand,
                                                     const int* __restrict__ gcnt,
                                                     const int* __restrict__ gflag,
                                                     float* __restrict__ out) {
    int row = blockIdx.x * 4 + (threadIdx.x >> 6);
    int lane = threadIdx.x & 63;

    // early self-row prefetch: row is always its own top-1 (sim = 1.0), so this
    // load is unconditionally needed and hides under the whole selection phase
    const float4* hr4 = (const float4*)(h + (size_t)row * D);
    float4 s0 = hr4[lane], s1 = hr4[64 + lane];

    int c = gcnt[row];

    float selv[K_TOP];
    int selj[K_TOP];

    if (c >= K_TOP && c <= CAPG && gflag[row] == 0) {
        const unsigned int* cr = gcand + (size_t)row * CAPG;
        unsigned int e[3];
#pragma unroll
        for (int q = 0; q < 3; q++) {
            int idx = lane + 64 * q;
            e[q] = (idx < c) ? cr[idx] : 0u;
        }
#pragma unroll
        for (int k = 0; k < K_TOP; k++) {
            unsigned int m = e[0];
            if (e[1] > m) m = e[1];
            if (e[2] > m) m = e[2];
#pragma unroll
            for (int off = 32; off > 0; off >>= 1) {
                unsigned int om = __shfl_xor(m, off, 64);
                if (om > m) m = om;
            }
            selv[k] = __uint_as_float(m & 0xFFFF0000u);
            selj[k] = (int)(m & 0x1FFFu);
#pragma unroll
            for (int q = 0; q < 3; q++)
                if (e[q] == m) e[q] = 0u;   // entries unique (distinct cols)
        }
    } else {
        // exact brute-force fallback over fp8 rows (rare; cheap insurance)
        float vals[K_TOP];
        int idxs[K_TOP];
#pragma unroll
        for (int q = 0; q < K_TOP; q++) { vals[q] = -3e38f; idxs[q] = 0; }
        float minv = -3e38f;
        int minp = 0;
        const unsigned int* rp = (const unsigned int*)(hq + (size_t)row * D);
        for (int col = lane; col < N; col += 64) {
            const unsigned int* cp = (const unsigned int*)(hq + (size_t)col * D);
            float s = 0.f;
            for (int k4 = 0; k4 < D / 4; k4++) {
                unsigned int ra = rp[k4], ca = cp[k4];
                s += __builtin_amdgcn_cvt_f32_fp8(ra, 0) * __builtin_amdgcn_cvt_f32_fp8(ca, 0);
                s += __builtin_amdgcn_cvt_f32_fp8(ra, 1) * __builtin_amdgcn_cvt_f32_fp8(ca, 1);
                s += __builtin_amdgcn_cvt_f32_fp8(ra, 2) * __builtin_amdgcn_cvt_f32_fp8(ca, 2);
                s += __builtin_amdgcn_cvt_f32_fp8(ra, 3) * __builtin_amdgcn_cvt_f32_fp8(ca, 3);
            }
            if (col == row) s = 1.0f;
            if (s > minv) {
                vals[minp] = s; idxs[minp] = col;
                minv = vals[0]; minp = 0;
#pragma unroll
                for (int q = 1; q < K_TOP; q++)
                    if (vals[q] < minv) { minv = vals[q]; minp = q; }
            }
        }
        for (int k = 0; k < K_TOP; k++) {
            float bv = vals[0]; int bp = 0;
#pragma unroll
            for (int q = 1; q < K_TOP; q++)
                if (vals[q] > bv) { bv = vals[q]; bp = q; }
            float v = bv; int j = idxs[bp]; int src = lane;
#pragma unroll
            for (int off = 32; off > 0; off >>= 1) {
                float ov = __shfl_xor(v, off, 64);
                int oj = __shfl_xor(j, off, 64);
                int os = __shfl_xor(src, off, 64);
                if (ov > v || (ov == v && os < src)) { v = ov; j = oj; src = os; }
            }
            selv[k] = __uint_as_float((unsigned int)(bf16_bits_rne(v) << 16));
            selj[k] = j;
            if (lane == src) vals[bp] = -3e38f;
        }
    }

    // batch-issue all neighbor fp8 row loads (12-deep MLP) + their norms
    unsigned int na[K_TOP], nb[K_TOP];
    float wn[K_TOP];
#pragma unroll
    for (int q = 0; q < K_TOP; q++) {
        const unsigned int* r32 = (const unsigned int*)(hq + (size_t)selj[q] * D);
        na[q] = r32[lane];
        nb[q] = r32[64 + lane];
        wn[q] = norms[selj[q]];
    }

    float mx = selv[0];
    float beta[K_TOP];
    float sum = 0.f;
#pragma unroll
    for (int q = 0; q < K_TOP; q++) { beta[q] = __expf(THETA * (selv[q] - mx)); sum += beta[q]; }
    float rs = 1.0f / sum;

    // lane owns output elems [lane*4,+4) and [256+lane*4,+4)
    float acc[8];
#pragma unroll
    for (int ee = 0; ee < 8; ee++) acc[ee] = 0.f;
#pragma unroll
    for (int q = 0; q < K_TOP; q++) {
        float w = beta[q] * rs;
        if (selj[q] == row) {   // wave-uniform; dominant term stays fp32-exact
            acc[0] += w * s0.x; acc[1] += w * s0.y; acc[2] += w * s0.z; acc[3] += w * s0.w;
            acc[4] += w * s1.x; acc[5] += w * s1.y; acc[6] += w * s1.z; acc[7] += w * s1.w;
        } else {                // neighbors (weight ~2e-4): fp8 row x norm
            float wj = w * wn[q];
            acc[0] += wj * __builtin_amdgcn_cvt_f32_fp8(na[q], 0);
            acc[1] += wj * __builtin_amdgcn_cvt_f32_fp8(na[q], 1);
            acc[2] += wj * __builtin_amdgcn_cvt_f32_fp8(na[q], 2);
            acc[3] += wj * __builtin_amdgcn_cvt_f32_fp8(na[q], 3);
            acc[4] += wj * __builtin_amdgcn_cvt_f32_fp8(nb[q], 0);
            acc[5] += wj * __builtin_amdgcn_cvt_f32_fp8(nb[q], 1);
            acc[6] += wj * __builtin_amdgcn_cvt_f32_fp8(nb[q], 2);
            acc[7] += wj * __builtin_amdgcn_cvt_f32_fp8(nb[q], 3);
        }
    }
    float4* o4 = (float4*)(out + (size_t)row * D);
    o4[lane] = make_float4(acc[0], acc[1], acc[2], acc[3]);
    o4[64 + lane] = make_float4(acc[4], acc[5], acc[6], acc[7]);
}

extern "C" void kernel_launch(void* const* d_in, const int* in_sizes, int n_in,
                              void* d_out, int out_size, void* d_ws, size_t ws_size,
                              hipStream_t stream) {
    const float* h = (const float*)d_in[0];
    float* out = (float*)d_out;

    char* ws = (char*)d_ws;
    unsigned char* hq = (unsigned char*)ws;                      // 4 MB fp8
    size_t off = (size_t)N * D;
    float* norms = (float*)(ws + off);                           // 32 KB
    int* gcnt = (int*)(ws + off + (size_t)N * 4);                // 32 KB
    int* gflag = (int*)(ws + off + (size_t)N * 8);               // 32 KB
    unsigned int* gcand = (unsigned int*)(ws + off + (size_t)N * 12);  // 6 MB

    norm_kernel<<<N / 4, 256, 0, stream>>>(h, hq, norms, gcnt, gflag);
    simfp8_kernel<<<NBLK, 256, 0, stream>>>(hq, gcand, gcnt, gflag);
    gather_kernel<<<N / 4, 256, 0, stream>>>(h, hq, norms, gcand, gcnt, gflag, out);
}